// Round 7
// baseline (528.884 us; speedup 1.0000x reference)
//
#include <hip/hip_runtime.h>
#include <cstddef>

#define NB 16384
#define NGRP 8
#define AS 1160   // act batch stride in halves (16*72 + 8 pad)

typedef __attribute__((ext_vector_type(8))) _Float16 half8;
typedef __attribute__((ext_vector_type(4))) _Float16 half4;
typedef __attribute__((ext_vector_type(4))) float f32x4;
typedef __attribute__((ext_vector_type(2))) float f32x2;
typedef __attribute__((ext_vector_type(16))) float f32x16;

// ---- ws float offsets ----
#define OFF_W1T 0                      // 12*64
#define OFF_SC1 768
#define OFF_SH1 832
#define OFF_SC2 896
#define OFF_SH2 960
#define OFF_SC3 1024
#define OFF_SH3 1088
#define OFF_PB  1152                   // 4*16
#define OFF_PBB 1216                   // 16
#define OFF_CO  1232                   // 16*64 -> 2256
#define OFF_W2H 2304                   // 20*2*64*8 halves = 10240 floats
#define OFF_W2L 12544                  // 10240 floats
#define OFF_W3H 22784                  // 28*2*64*8 halves = 14336 floats
#define OFF_W3L 37120                  // 14336 floats
#define OFF_SF  51456                  // NB*64
#define OFF_H   (51456 + NB*64)        // NB*16

static __device__ __forceinline__ f32x16 mfma16(half8 a, half8 b, f32x16 c) {
  return __builtin_amdgcn_mfma_f32_32x32x16_f16(a, b, c, 0, 0, 0);
}

// ============================ prep ============================
__global__ __launch_bounds__(256) void prep_kernel(
    const float* __restrict__ conv1_w, const float* __restrict__ conv1_b,
    const float* __restrict__ conv2_w, const float* __restrict__ conv2_b,
    const float* __restrict__ conv3_w, const float* __restrict__ conv3_b,
    const float* __restrict__ bn1_g, const float* __restrict__ bn1_b,
    const float* __restrict__ bn2_g, const float* __restrict__ bn2_b,
    const float* __restrict__ bn3_g, const float* __restrict__ bn3_b,
    const float* __restrict__ proj_w, const float* __restrict__ proj_b,
    const float* __restrict__ A, const float* __restrict__ Bm,
    const float* __restrict__ Cm, const float* __restrict__ out_w,
    float* __restrict__ ws)
{
  int tid = blockIdx.x * blockDim.x + threadIdx.x;
  int nt = gridDim.x * blockDim.x;
  const float s = rsqrtf(1.0f + 1e-5f);

  for (int i = tid; i < 64*12; i += nt) {       // w1t[(c*3+k)*64+o]
    int o = i & 63, rk = i >> 6;
    ws[OFF_W1T + i] = conv1_w[o*12 + rk];
  }
  for (int o = tid; o < 64; o += nt) {
    float s1 = bn1_g[o]*s, s2 = bn2_g[o]*s, s3 = bn3_g[o]*s;
    ws[OFF_SC1+o] = s1; ws[OFF_SH1+o] = s1*conv1_b[o] + bn1_b[o];
    ws[OFF_SC2+o] = s2; ws[OFF_SH2+o] = s2*conv2_b[o] + bn2_b[o];
    ws[OFF_SC3+o] = s3; ws[OFF_SH3+o] = s3*conv3_b[o] + bn3_b[o];
  }
  // conv2 A-fragments for 32x32x16, k = tap*64 + ic (tap-major), hi/lo split.
  {
    _Float16* w2h = (_Float16*)(ws + OFF_W2H);
    _Float16* w2l = (_Float16*)(ws + OFF_W2L);
    for (int i = tid; i < 20*2*64; i += nt) {
      int lane = i & 63, ot = (i >> 6) & 1, sk = i >> 7;
      int tap = sk >> 2, ic0 = (sk & 3)*16 + (lane >> 5)*8;
      int o = ot*32 + (lane & 31);
      #pragma unroll
      for (int j = 0; j < 8; ++j) {
        float w = conv2_w[o*320 + (ic0 + j)*5 + tap];
        _Float16 hi = (_Float16)w;
        w2h[(size_t)i*8 + j] = hi;
        w2l[(size_t)i*8 + j] = (_Float16)(w - (float)hi);
      }
    }
  }
  {
    _Float16* w3h = (_Float16*)(ws + OFF_W3H);
    _Float16* w3l = (_Float16*)(ws + OFF_W3L);
    for (int i = tid; i < 28*2*64; i += nt) {
      int lane = i & 63, ot = (i >> 6) & 1, sk = i >> 7;
      int tap = sk >> 2, ic0 = (sk & 3)*16 + (lane >> 5)*8;
      int o = ot*32 + (lane & 31);
      #pragma unroll
      for (int j = 0; j < 8; ++j) {
        float w = conv3_w[o*448 + (ic0 + j)*7 + tap];
        _Float16 hi = (_Float16)w;
        w3h[(size_t)i*8 + j] = hi;
        w3l[(size_t)i*8 + j] = (_Float16)(w - (float)hi);
      }
    }
  }
  // PB[c][j] = sum_m proj_w[c][m]*Bm[m][j]
  for (int i = tid; i < 64; i += nt) {
    int c = i >> 4, j = i & 15;
    float acc = 0.f;
    for (int m = 0; m < 64; ++m) acc += proj_w[c*64+m]*Bm[m*16+j];
    ws[OFF_PB + i] = acc;
  }
  for (int j = tid; j < 16; j += nt) {
    float acc = 0.f;
    for (int m = 0; m < 64; ++m) acc += proj_b[m]*Bm[m*16+j];
    ws[OFF_PBB + j] = acc;
  }
  // CO[j][o] = sum_m Cm[j][m]*out_w[m][o]
  for (int i = tid; i < 16*64; i += nt) {
    int j = i >> 6, o = i & 63;
    float acc = 0.f;
    for (int m = 0; m < 64; ++m) acc += Cm[j*64+m]*out_w[m*64+o];
    ws[OFF_CO + i] = acc;
  }
}

// ============================ conv stack ============================
// Roles: waves 0-1 = c2 (ot=wid, 2 pairs); waves 2-5 = c3 ((ot,pair) split + conv1).
// Register budget lesson (r3-r6): compiler allocates 128 arch VGPRs, period.
// Anything above spills to scratch (531->72 MB HBM spill traffic over 3 rounds).
// So: EXACTLY 20 hi-frags (80 VGPR) resident per wave; ALL lo-weights (and
// c3's hi sk>=20) stream from global via L2 (images total 120 KB, L2-resident).
// Peak liveness ~118 < 128 -> zero spill. w3ls LDS buffer deleted (56 KB) ->
// LDS 74 KB -> 2 blocks/CU; NGRP=8 doubles grid to 512 for 2-block co-residency.
__global__ __launch_bounds__(384) void conv_kernel(
    const float* __restrict__ x, const float* __restrict__ wsr,
    float* __restrict__ sfp)
{
  __shared__ __align__(16) _Float16 a1h[2][4*AS];
  __shared__ __align__(16) _Float16 a1l[2][4*AS];
  __shared__ __align__(16) _Float16 a2h[2][4*AS];
  __shared__ __align__(16) _Float16 a2l[2][4*AS];

  const int tid = threadIdx.x;
  const int lane = tid & 63;
  const int wid = tid >> 6;
  const bool isC2 = (wid < 2);
  const int n = lane & 15;
  const int nc = (n < 10) ? n : 9;       // clamp; junk cols masked in epilogue
  const int kh8 = (lane >> 5) * 8;

  // zero acts (pads rely on this; valid slots rewritten per group)
  for (int i = tid; i < 4*AS; i += 384) {
    ((unsigned*)a1h)[i] = 0u; ((unsigned*)a1l)[i] = 0u;
    ((unsigned*)a2h)[i] = 0u; ((unsigned*)a2l)[i] = 0u;
  }

  // ---- resident hi-weight registers (20 frags = 80 VGPR), role-dependent:
  //   c2 waves: wreg[sk] = w2h[sk], sk 0..19 (full conv2 hi)
  //   c3 waves: wreg[sk] = w3h[sk], sk 0..19 (hi sk 20..27 streamed)
  half8 wreg[20];
  float w1c[12], sc1 = 0.f, sh1 = 0.f;
  int ot3 = 0, lb3 = 0, idx3 = 0;

  if (isC2) {
    const int ot = wid;
    #pragma unroll
    for (int sk = 0; sk < 20; ++sk)
      wreg[sk] = *(const half8*)(wsr + OFF_W2H + (size_t)((sk*2 + ot)*64 + lane)*4);
  } else {
    idx3 = wid - 2;
    ot3 = idx3 & 1;
    lb3 = 2*(idx3 >> 1) + ((lane >> 4) & 1);
    #pragma unroll
    for (int sk = 0; sk < 20; ++sk)
      wreg[sk] = *(const half8*)(wsr + OFF_W3H + (size_t)((sk*2 + ot3)*64 + lane)*4);
    #pragma unroll
    for (int i = 0; i < 12; ++i) w1c[i] = wsr[OFF_W1T + i*64 + lane];
    sc1 = wsr[OFF_SC1 + lane]; sh1 = wsr[OFF_SH1 + lane];
  }
  const int rq2 = 4*(lane >> 5) + wid*32;        // c2 row base (ot=wid)
  const int rq3 = 4*(lane >> 5) + ot3*32;        // c3 row base
  // stream base pointers (lane-resolved once)
  const float* w2l_p = wsr + OFF_W2L + (size_t)lane*4;   // + (sk*2+ot)*256
  const float* w3h_p = wsr + OFF_W3H + (size_t)lane*4;
  const float* w3l_p = wsr + OFF_W3L + (size_t)lane*4;

  __syncthreads();

  // c2 conv2 for one pair of one group
  auto conv2_pair = [&](int buf, int p) {
    const int lb = 2*p + ((lane >> 4) & 1);
    const _Float16* bhp = &a1h[buf][lb*AS];
    const _Float16* blp = &a1l[buf][lb*AS];
    const int ot = wid;
    f32x16 acc;
    #pragma unroll
    for (int r = 0; r < 16; ++r) acc[r] = 0.f;
    #pragma unroll
    for (int sk = 0; sk < 20; ++sk) {
      const int tap = sk >> 2, icb = (sk & 3)*16;
      const int off = (nc + tap + 1)*72 + icb + kh8;
      const half8 bh = *(const half8*)(bhp + off);
      const half8 bl = *(const half8*)(blp + off);
      const half8 wl = *(const half8*)(w2l_p + (size_t)(sk*2 + ot)*256);
      acc = mfma16(wreg[sk], bh, acc);
      acc = mfma16(wreg[sk], bl, acc);
      acc = mfma16(wl, bh, acc);
    }
    if (n < 10) {
      #pragma unroll
      for (int q = 0; q < 4; ++q) {
        const int rowb = 8*q + rq2;
        const f32x4 sc = *(const f32x4*)(wsr + OFF_SC2 + rowb);
        const f32x4 sh = *(const f32x4*)(wsr + OFF_SH2 + rowb);
        half4 h4, l4;
        #pragma unroll
        for (int r = 0; r < 4; ++r) {
          float v = sc[r]*acc[4*q + r] + sh[r];
          v = v > 0.f ? v : 0.f;
          _Float16 hi = (_Float16)v;
          h4[r] = hi;
          l4[r] = (_Float16)(v - (float)hi);
        }
        *(half4*)(&a2h[buf][lb*AS + (n + 3)*72 + rowb]) = h4;
        *(half4*)(&a2l[buf][lb*AS + (n + 3)*72 + rowb]) = l4;
      }
    }
  };

  for (int it = 0; it <= NGRP; ++it) {
    const int g = blockIdx.x*NGRP + it;
    const int cb = it & 1;       // buffers for group g
    // ---------------- Seg1 ----------------
    if (isC2) {
      if (it > 0) conv2_pair(cb ^ 1, 1);
    } else {
      if (it < NGRP) {
        // conv1 for batch g*4 + idx3 (fp32 VALU, lane = out channel)
        const size_t bi = (size_t)g*4 + idx3;
        float xv[4][12];
        #pragma unroll
        for (int c = 0; c < 4; ++c) { xv[c][0] = 0.f; xv[c][11] = 0.f; }
        #pragma unroll
        for (int tt = 0; tt < 10; ++tt)
          #pragma unroll
          for (int c = 0; c < 4; ++c)
            xv[c][1 + tt] = x[bi*400 + (90 + tt)*4 + c];
        float a1[10];
        #pragma unroll
        for (int t = 0; t < 10; ++t) a1[t] = 0.f;
        #pragma unroll
        for (int c = 0; c < 4; ++c)
          #pragma unroll
          for (int k = 0; k < 3; ++k) {
            const float wv = w1c[c*3 + k];
            #pragma unroll
            for (int t = 0; t < 10; ++t) a1[t] += wv * xv[c][t + k];
          }
        #pragma unroll
        for (int t = 0; t < 10; ++t) {
          float v = sc1*a1[t] + sh1;
          v = v > 0.f ? v : 0.f;
          _Float16 hi = (_Float16)v;
          a1h[cb][idx3*AS + (3 + t)*72 + lane] = hi;
          a1l[cb][idx3*AS + (3 + t)*72 + lane] = (_Float16)(v - (float)hi);
        }
      }
    }
    __syncthreads();
    // ---------------- Seg2 ----------------
    if (isC2) {
      if (it < NGRP) conv2_pair(cb, 0);
    } else {
      if (it > 0) {
        const int rb = cb ^ 1;   // act2 buffer of group g-1
        const _Float16* bhp = &a2h[rb][lb3*AS];
        const _Float16* blp = &a2l[rb][lb3*AS];
        f32x16 acc;
        #pragma unroll
        for (int r = 0; r < 16; ++r) acc[r] = 0.f;
        #pragma unroll
        for (int sk = 0; sk < 28; ++sk) {
          const int tap = sk >> 2, icb = (sk & 3)*16;
          const int off = (nc + tap)*72 + icb + kh8;
          const half8 bh = *(const half8*)(bhp + off);
          const half8 bl = *(const half8*)(blp + off);
          const half8 wl = *(const half8*)(w3l_p + (size_t)(sk*2 + ot3)*256);
          const half8 wh = (sk < 20) ? wreg[sk < 20 ? sk : 0]
                                     : *(const half8*)(w3h_p + (size_t)(sk*2 + ot3)*256);
          acc = mfma16(wh, bh, acc);
          acc = mfma16(wh, bl, acc);
          acc = mfma16(wl, bh, acc);
        }
        #pragma unroll
        for (int q = 0; q < 4; ++q) {
          const int rowb = 8*q + rq3;
          const f32x4 sc = *(const f32x4*)(wsr + OFF_SC3 + rowb);
          const f32x4 sh = *(const f32x4*)(wsr + OFF_SH3 + rowb);
          f32x4 v;
          #pragma unroll
          for (int r = 0; r < 4; ++r) {
            float t = sc[r]*acc[4*q + r] + sh[r];
            t = t > 0.f ? t : 0.f;
            v[r] = (n < 10) ? t : 0.f;
          }
          #pragma unroll
          for (int r = 0; r < 4; ++r) {
            v[r] += __shfl_xor(v[r], 1, 16);
            v[r] += __shfl_xor(v[r], 2, 16);
            v[r] += __shfl_xor(v[r], 4, 16);
            v[r] += __shfl_xor(v[r], 8, 16);
          }
          if (n == 0)
            *(f32x4*)(sfp + ((size_t)(g - 1)*4 + lb3)*64 + rowb) = v * 0.1f;
        }
      }
    }
    __syncthreads();
  }
}

// ============================ RNN ============================
__global__ __launch_bounds__(256) void rnn_kernel(
    const float* __restrict__ x, const float* __restrict__ wsr,
    const float* __restrict__ A, float* __restrict__ hout)
{
  __shared__ float hbuf[16][20];   // padded rows; 16 groups per block
  int tid = blockIdx.x * 256 + threadIdx.x;
  int b = tid >> 4;
  int j = tid & 15;
  int g = threadIdx.x >> 4;

  float Arow[16];
  const float4* Ap = (const float4*)(A + j*16);
  #pragma unroll
  for (int q = 0; q < 4; ++q) { float4 v = Ap[q]; Arow[4*q]=v.x; Arow[4*q+1]=v.y; Arow[4*q+2]=v.z; Arow[4*q+3]=v.w; }
  float pb0 = wsr[OFF_PB + 0*16 + j];
  float pb1 = wsr[OFF_PB + 1*16 + j];
  float pb2 = wsr[OFF_PB + 2*16 + j];
  float pb3 = wsr[OFF_PB + 3*16 + j];
  float biasv = wsr[OFF_PBB + j];

  const float4* xb = (const float4*)(x + (size_t)b*400);
  float h = 0.f;
  float4 cur[5], nxt[5];
  #pragma unroll
  for (int q = 0; q < 5; ++q) cur[q] = xb[q];
  for (int tc = 0; tc < 100; tc += 5) {
    if (tc + 5 < 100) {
      #pragma unroll
      for (int q = 0; q < 5; ++q) nxt[q] = xb[tc+5+q];
    }
    #pragma unroll
    for (int q = 0; q < 5; ++q) {
      float4 cx = cur[q];
      float u = biasv + cx.x*pb0 + cx.y*pb1 + cx.z*pb2 + cx.w*pb3;
      hbuf[g][j] = h;                       // same-wave LDS broadcast
      const f32x4* hp = (const f32x4*)hbuf[g];
      #pragma unroll
      for (int qq = 0; qq < 4; ++qq) {
        f32x4 hv = hp[qq];
        u += hv[0]*Arow[4*qq] + hv[1]*Arow[4*qq+1] + hv[2]*Arow[4*qq+2] + hv[3]*Arow[4*qq+3];
      }
      float e = __expf(2.f*u);
      h = 1.f - 2.f/(e + 1.f);
    }
    #pragma unroll
    for (int q = 0; q < 5; ++q) cur[q] = nxt[q];
  }
  hout[(size_t)b*16 + j] = h;
}

// ============================ tail ============================
// lane = (b4 = lane>>4, og = lane&15): 4 batches/wave, o-quad per lane.
// All stage buffers are wave-private per (wid) -> no in-loop barriers.
__global__ __launch_bounds__(256) void tail_kernel(
    const float* __restrict__ wsr,
    const float* __restrict__ g1_w, const float* __restrict__ g1_b,
    const float* __restrict__ g2_w, const float* __restrict__ g2_b,
    const float* __restrict__ h1_w, const float* __restrict__ h1_b,
    const float* __restrict__ h2_w, const float* __restrict__ h2_b,
    const float* __restrict__ out_b, float* __restrict__ out)
{
  __shared__ float sG1[128*64];   // 32 KB, [k][o]
  __shared__ float sG2[64*64];    // 16 KB
  __shared__ float sH1[64*32];    // 8 KB
  __shared__ float sH2[32*3];
  __shared__ float sCO[16*64];    // 4 KB
  __shared__ float wbuf[16][132];
  __shared__ float tbuf[16][68];
  __shared__ float t2buf[16][36];
  __shared__ float hbuf[4][64];
  int tid = threadIdx.x;
  for (int i = tid; i < 128*64; i += 256) sG1[i] = g1_w[i];
  for (int i = tid; i < 64*64; i += 256) sG2[i] = g2_w[i];
  for (int i = tid; i < 64*32; i += 256) sH1[i] = h1_w[i];
  for (int i = tid; i < 96; i += 256) sH2[i] = h2_w[i];
  for (int i = tid; i < 16*64; i += 256) sCO[i] = wsr[OFF_CO + i];
  __syncthreads();

  const int lane = tid & 63, wid = tid >> 6;
  const int b4 = lane >> 4, og = lane & 15;
  const int wb = wid*4 + b4;
  const float* sf = wsr + OFF_SF;
  const float* hws = wsr + OFF_H;
  const f32x4 g1b4 = *(const f32x4*)(g1_b + 4*og);
  const f32x4 g2b4 = *(const f32x4*)(g2_b + 4*og);
  const f32x4 ob4  = *(const f32x4*)(out_b + 4*og);
  const f32x2 h1b2 = *(const f32x2*)(h1_b + 2*og);
  const float h2bv = (og < 3) ? h2_b[og] : 0.f;

  for (int seg = 0; seg < 4; ++seg) {
    const int wq = blockIdx.x*64 + seg*16 + wid*4;
    const int batch = wq + b4;
    hbuf[wid][lane] = hws[(size_t)wq*16 + lane];
    const f32x4 sfv = *(const f32x4*)(sf + (size_t)batch*64 + 4*og);
    f32x4 lcv = ob4;
    #pragma unroll
    for (int j = 0; j < 16; ++j) {
      const float hj = hbuf[wid][b4*16 + j];
      const f32x4 co = *(const f32x4*)(sCO + j*64 + 4*og);
      lcv += hj * co;
    }
    *(f32x4*)(&wbuf[wb][4*og]) = sfv;
    *(f32x4*)(&wbuf[wb][64 + 4*og]) = lcv;
    // L1: combined(128) @ g1 -> tanh
    f32x4 u = g1b4;
    #pragma unroll 8
    for (int k = 0; k < 128; ++k)
      u += wbuf[wb][k] * *(const f32x4*)(sG1 + k*64 + 4*og);
    f32x4 t1;
    #pragma unroll
    for (int r = 0; r < 4; ++r) {
      float e = __expf(2.f*u[r]);
      t1[r] = 1.f - 2.f/(e + 1.f);
    }
    *(f32x4*)(&tbuf[wb][4*og]) = t1;
    // L2: t1(64) @ g2 -> sigmoid -> gate
    f32x4 u2 = g2b4;
    #pragma unroll 8
    for (int k = 0; k < 64; ++k)
      u2 += tbuf[wb][k] * *(const f32x4*)(sG2 + k*64 + 4*og);
    f32x4 filt;
    #pragma unroll
    for (int r = 0; r < 4; ++r)
      filt[r] = sfv[r] / (1.f + __expf(-u2[r]));
    *(f32x4*)(&wbuf[wb][4*og]) = filt;
    // L3: filt(64) @ h1 -> relu (32 outs: 2 per lane)
    f32x2 r2 = h1b2;
    #pragma unroll 8
    for (int k = 0; k < 64; ++k)
      r2 += wbuf[wb][k] * *(const f32x2*)(sH1 + k*32 + 2*og);
    r2[0] = fmaxf(r2[0], 0.f); r2[1] = fmaxf(r2[1], 0.f);
    *(f32x2*)(&t2buf[wb][2*og]) = r2;
    // L4: (32) @ h2 -> 3 logits
    if (og < 3) {
      float a = h2bv;
      #pragma unroll
      for (int k = 0; k < 32; ++k) a += t2buf[wb][k] * sH2[k*3 + og];
      out[(size_t)batch*3 + og] = a;
    }
  }
}

// ============================ launch ============================
extern "C" void kernel_launch(void* const* d_in, const int* in_sizes, int n_in,
                              void* d_out, int out_size, void* d_ws, size_t ws_size,
                              hipStream_t stream) {
  const float* x       = (const float*)d_in[0];
  const float* conv1_w = (const float*)d_in[1];
  const float* conv1_b = (const float*)d_in[2];
  const float* conv2_w = (const float*)d_in[3];
  const float* conv2_b = (const float*)d_in[4];
  const float* conv3_w = (const float*)d_in[5];
  const float* conv3_b = (const float*)d_in[6];
  const float* bn1_g   = (const float*)d_in[7];
  const float* bn1_b   = (const float*)d_in[8];
  const float* bn2_g   = (const float*)d_in[9];
  const float* bn2_b   = (const float*)d_in[10];
  const float* bn3_g   = (const float*)d_in[11];
  const float* bn3_b   = (const float*)d_in[12];
  const float* proj_w  = (const float*)d_in[13];
  const float* proj_b  = (const float*)d_in[14];
  const float* A       = (const float*)d_in[15];
  const float* Bm      = (const float*)d_in[16];
  const float* Cm      = (const float*)d_in[17];
  const float* out_w   = (const float*)d_in[18];
  const float* out_b   = (const float*)d_in[19];
  const float* g1_w    = (const float*)d_in[20];
  const float* g1_b    = (const float*)d_in[21];
  const float* g2_w    = (const float*)d_in[22];
  const float* g2_b    = (const float*)d_in[23];
  const float* h1_w    = (const float*)d_in[24];
  const float* h1_b    = (const float*)d_in[25];
  const float* h2_w    = (const float*)d_in[26];
  const float* h2_b    = (const float*)d_in[27];
  float* ws = (float*)d_ws;
  float* out = (float*)d_out;

  prep_kernel<<<64, 256, 0, stream>>>(conv1_w, conv1_b, conv2_w, conv2_b,
      conv3_w, conv3_b, bn1_g, bn1_b, bn2_g, bn2_b, bn3_g, bn3_b,
      proj_w, proj_b, A, Bm, Cm, out_w, ws);
  conv_kernel<<<NB/(4*NGRP), 384, 0, stream>>>(x, ws, ws + OFF_SF);
  rnn_kernel<<<NB*16/256, 256, 0, stream>>>(x, ws, A, ws + OFF_H);
  tail_kernel<<<NB/64, 256, 0, stream>>>(ws, g1_w, g1_b, g2_w, g2_b,
      h1_w, h1_b, h2_w, h2_b, out_b, out);
}

// Round 8
// 332.801 us; speedup vs baseline: 1.5892x; 1.5892x over previous
//
#include <hip/hip_runtime.h>
#include <cstddef>

#define NB 16384
#define ITER 4
#define TS 720    // act batch stride in halves (10 slots * 72)

typedef __attribute__((ext_vector_type(8))) _Float16 half8;
typedef __attribute__((ext_vector_type(4))) _Float16 half4;
typedef __attribute__((ext_vector_type(4))) float f32x4;
typedef __attribute__((ext_vector_type(2))) float f32x2;
typedef __attribute__((ext_vector_type(16))) float f32x16;

// ---- ws float offsets ----
#define OFF_W1T 0                      // 12*64
#define OFF_SC1 768
#define OFF_SH1 832
#define OFF_SC2 896
#define OFF_SH2 960
#define OFF_SC3 1024
#define OFF_SH3 1088
#define OFF_PB  1152                   // 4*16
#define OFF_PBB 1216                   // 16
#define OFF_CO  1232                   // 16*64 -> 2256
#define OFF_W2H 2304                   // 10240 floats (w2 hi frags)
#define OFF_W2L 12544                  // 10240 floats (contiguous after W2H)
#define OFF_W3H 22784                  // 14336 floats
#define OFF_W3L 37120                  // 14336 floats (contiguous after W3H)
#define OFF_SF  51456                  // NB*64
#define OFF_H   (51456 + NB*64)        // NB*16

static __device__ __forceinline__ f32x16 mfma32(half8 a, half8 b, f32x16 c) {
  return __builtin_amdgcn_mfma_f32_32x32x16_f16(a, b, c, 0, 0, 0);
}
static __device__ __forceinline__ f32x4 mfma16(half4 a, half4 b, f32x4 c) {
  return __builtin_amdgcn_mfma_f32_16x16x16f16(a, b, c, 0, 0, 0);
}

// ============================ prep ============================
__global__ __launch_bounds__(256) void prep_kernel(
    const float* __restrict__ conv1_w, const float* __restrict__ conv1_b,
    const float* __restrict__ conv2_w, const float* __restrict__ conv2_b,
    const float* __restrict__ conv3_w, const float* __restrict__ conv3_b,
    const float* __restrict__ bn1_g, const float* __restrict__ bn1_b,
    const float* __restrict__ bn2_g, const float* __restrict__ bn2_b,
    const float* __restrict__ bn3_g, const float* __restrict__ bn3_b,
    const float* __restrict__ proj_w, const float* __restrict__ proj_b,
    const float* __restrict__ A, const float* __restrict__ Bm,
    const float* __restrict__ Cm, const float* __restrict__ out_w,
    float* __restrict__ ws)
{
  int tid = blockIdx.x * blockDim.x + threadIdx.x;
  int nt = gridDim.x * blockDim.x;
  const float s = rsqrtf(1.0f + 1e-5f);

  for (int i = tid; i < 64*12; i += nt) {       // w1t[(c*3+k)*64+o]
    int o = i & 63, rk = i >> 6;
    ws[OFF_W1T + i] = conv1_w[o*12 + rk];
  }
  for (int o = tid; o < 64; o += nt) {
    float s1 = bn1_g[o]*s, s2 = bn2_g[o]*s, s3 = bn3_g[o]*s;
    ws[OFF_SC1+o] = s1; ws[OFF_SH1+o] = s1*conv1_b[o] + bn1_b[o];
    ws[OFF_SC2+o] = s2; ws[OFF_SH2+o] = s2*conv2_b[o] + bn2_b[o];
    ws[OFF_SC3+o] = s3; ws[OFF_SH3+o] = s3*conv3_b[o] + bn3_b[o];
  }
  // conv2 A-fragments for 32x32x16, k = tap*64 + ic (tap-major), hi/lo split.
  // frag i = sk*2+ot; lane l: o = ot*32+(l&31), ic = (sk&3)*16+(l>>5)*8+j
  {
    _Float16* w2h = (_Float16*)(ws + OFF_W2H);
    _Float16* w2l = (_Float16*)(ws + OFF_W2L);
    for (int i = tid; i < 20*2*64; i += nt) {
      int lane = i & 63, ot = (i >> 6) & 1, sk = i >> 7;
      int tap = sk >> 2, ic0 = (sk & 3)*16 + (lane >> 5)*8;
      int o = ot*32 + (lane & 31);
      #pragma unroll
      for (int j = 0; j < 8; ++j) {
        float w = conv2_w[o*320 + (ic0 + j)*5 + tap];
        _Float16 hi = (_Float16)w;
        w2h[(size_t)i*8 + j] = hi;
        w2l[(size_t)i*8 + j] = (_Float16)(w - (float)hi);
      }
    }
  }
  {
    _Float16* w3h = (_Float16*)(ws + OFF_W3H);
    _Float16* w3l = (_Float16*)(ws + OFF_W3L);
    for (int i = tid; i < 28*2*64; i += nt) {
      int lane = i & 63, ot = (i >> 6) & 1, sk = i >> 7;
      int tap = sk >> 2, ic0 = (sk & 3)*16 + (lane >> 5)*8;
      int o = ot*32 + (lane & 31);
      #pragma unroll
      for (int j = 0; j < 8; ++j) {
        float w = conv3_w[o*448 + (ic0 + j)*7 + tap];
        _Float16 hi = (_Float16)w;
        w3h[(size_t)i*8 + j] = hi;
        w3l[(size_t)i*8 + j] = (_Float16)(w - (float)hi);
      }
    }
  }
  // PB[c][j] = sum_m proj_w[c][m]*Bm[m][j]
  for (int i = tid; i < 64; i += nt) {
    int c = i >> 4, j = i & 15;
    float acc = 0.f;
    for (int m = 0; m < 64; ++m) acc += proj_w[c*64+m]*Bm[m*16+j];
    ws[OFF_PB + i] = acc;
  }
  for (int j = tid; j < 16; j += nt) {
    float acc = 0.f;
    for (int m = 0; m < 64; ++m) acc += proj_b[m]*Bm[m*16+j];
    ws[OFF_PBB + j] = acc;
  }
  // CO[j][o] = sum_m Cm[j][m]*out_w[m][o]
  for (int i = tid; i < 16*64; i += nt) {
    int j = i >> 6, o = i & 63;
    float acc = 0.f;
    for (int m = 0; m < 64; ++m) acc += Cm[j*64+m]*out_w[m*64+o];
    ws[OFF_CO + i] = acc;
  }
}

// ============================ conv stack ============================
// r3-r7 lesson: weight-resident-in-VGPR schemes all spill (allocator pins 128).
// This version holds ZERO weights in registers: all fragments come from LDS
// via ds_read_b128. One 112 KB LDS region is phase-swapped: w2(hi+lo, 80 KB)
// during conv2, w3(hi+lo, 112 KB) during conv3; reloaded from L2-resident ws
// images each iteration. Acts use 10 slots (no pad slots); out-of-range taps
// are zeroed by per-lane cndmask on the loaded value.
// Block = 256 thr = 4 waves; wave = (group 0/1, pair 0/1); each wave computes
// BOTH otiles (acc0/acc1) so B-fragments are read once. ITER=4 iterations of
// 8 batches -> 32 batches/block, grid = NB/32 = 512.
__global__ __launch_bounds__(256) void conv_kernel(
    const float* __restrict__ x, const float* __restrict__ wsr,
    float* __restrict__ sfp)
{
  __shared__ __align__(16) _Float16 sW[57344];            // 112 KB swap region
  __shared__ __align__(16) _Float16 a1h[8][TS], a1l[8][TS];
  __shared__ __align__(16) _Float16 a2h[8][TS], a2l[8][TS]; // 4*11.25 KB

  const int tid = threadIdx.x;
  const int lane = tid & 63;
  const int wid = tid >> 6;
  const int n = lane & 15;
  const int nc = (n < 10) ? n : 9;      // clamp; junk cols masked in epilogue
  const int kh8 = (lane >> 5) * 8;
  const int rq = 4 * (lane >> 5);
  const int grp = wid >> 1;             // local group 0/1
  const int pr = wid & 1;               // pair within group
  const int lb0 = grp*4 + pr*2;         // wave's first local batch
  const int lbL = lb0 + ((lane >> 4) & 1);  // lane's column batch

  const half8 z8 = {};
  const float sc1 = wsr[OFF_SC1 + lane], sh1 = wsr[OFF_SH1 + lane];

  for (int it = 0; it < ITER; ++it) {
    const size_t gbase = (size_t)blockIdx.x*(8*ITER) + (size_t)it*8;

    // ---- Phase A: stage w2 hi+lo into sW (contiguous image) + conv1 ----
    {
      const f32x4* src = (const f32x4*)(wsr + OFF_W2H);
      f32x4* dst = (f32x4*)sW;
      for (int i = tid; i < 5120; i += 256) dst[i] = src[i];
    }
    #pragma unroll
    for (int bb = 0; bb < 2; ++bb) {
      const int lb = lb0 + bb;
      const size_t gb = gbase + lb;
      float xv[4][12];
      #pragma unroll
      for (int c = 0; c < 4; ++c) { xv[c][0] = 0.f; xv[c][11] = 0.f; }
      #pragma unroll
      for (int tt = 0; tt < 10; ++tt)
        #pragma unroll
        for (int c = 0; c < 4; ++c)
          xv[c][1 + tt] = x[gb*400 + (90 + tt)*4 + c];
      float a1[10];
      #pragma unroll
      for (int t = 0; t < 10; ++t) a1[t] = 0.f;
      #pragma unroll
      for (int c = 0; c < 4; ++c)
        #pragma unroll
        for (int k = 0; k < 3; ++k) {
          const float wv = wsr[OFF_W1T + (c*3 + k)*64 + lane];
          #pragma unroll
          for (int t = 0; t < 10; ++t) a1[t] += wv * xv[c][t + k];
        }
      #pragma unroll
      for (int t = 0; t < 10; ++t) {
        float v = sc1*a1[t] + sh1;
        v = v > 0.f ? v : 0.f;
        _Float16 hi = (_Float16)v;
        a1h[lb][t*72 + lane] = hi;
        a1l[lb][t*72 + lane] = (_Float16)(v - (float)hi);
      }
    }
    __syncthreads();

    // ---- Phase B: conv2 (both otiles) for this wave's pair ----
    {
      f32x16 acc0, acc1;
      #pragma unroll
      for (int r = 0; r < 16; ++r) { acc0[r] = 0.f; acc1[r] = 0.f; }
      const _Float16* bhp = &a1h[lbL][0];
      const _Float16* blp = &a1l[lbL][0];
      #pragma unroll
      for (int sk = 0; sk < 20; ++sk) {
        const int tap = sk >> 2, icb = (sk & 3)*16;
        const int t = nc + tap - 2;                 // conv2 input t
        const int tc = t < 0 ? 0 : (t > 9 ? 9 : t);
        const bool valid = (t >= 0) & (t <= 9);
        const int off = tc*72 + icb + kh8;
        half8 bh = *(const half8*)(bhp + off);
        half8 bl = *(const half8*)(blp + off);
        bh = valid ? bh : z8;
        bl = valid ? bl : z8;
        const half8 wh0 = *(const half8*)(sW + (size_t)(sk*2 + 0)*512 + lane*8);
        const half8 wh1 = *(const half8*)(sW + (size_t)(sk*2 + 1)*512 + lane*8);
        const half8 wl0 = *(const half8*)(sW + (size_t)(40 + sk*2)*512 + lane*8);
        const half8 wl1 = *(const half8*)(sW + (size_t)(41 + sk*2)*512 + lane*8);
        acc0 = mfma32(wh0, bh, acc0);
        acc0 = mfma32(wh0, bl, acc0);
        acc0 = mfma32(wl0, bh, acc0);
        acc1 = mfma32(wh1, bh, acc1);
        acc1 = mfma32(wh1, bl, acc1);
        acc1 = mfma32(wl1, bh, acc1);
      }
      if (n < 10) {
        auto epi = [&](const f32x16& ac, int ot) {
          #pragma unroll
          for (int q = 0; q < 4; ++q) {
            const int rowb = 8*q + rq + ot*32;
            const f32x4 sc = *(const f32x4*)(wsr + OFF_SC2 + rowb);
            const f32x4 sh = *(const f32x4*)(wsr + OFF_SH2 + rowb);
            half4 h4, l4;
            #pragma unroll
            for (int r = 0; r < 4; ++r) {
              float v = sc[r]*ac[4*q + r] + sh[r];
              v = v > 0.f ? v : 0.f;
              _Float16 hi = (_Float16)v;
              h4[r] = hi;
              l4[r] = (_Float16)(v - (float)hi);
            }
            *(half4*)(&a2h[lbL][n*72 + rowb]) = h4;
            *(half4*)(&a2l[lbL][n*72 + rowb]) = l4;
          }
        };
        epi(acc0, 0);
        epi(acc1, 1);
      }
    }
    __syncthreads();

    // ---- Phase C: swap in w3 hi+lo (contiguous image) ----
    {
      const f32x4* src = (const f32x4*)(wsr + OFF_W3H);
      f32x4* dst = (f32x4*)sW;
      for (int i = tid; i < 7168; i += 256) dst[i] = src[i];
    }
    __syncthreads();

    // ---- Phase D: conv3 (both otiles) + mean + store ----
    {
      f32x16 acc0, acc1;
      #pragma unroll
      for (int r = 0; r < 16; ++r) { acc0[r] = 0.f; acc1[r] = 0.f; }
      const _Float16* bhp = &a2h[lbL][0];
      const _Float16* blp = &a2l[lbL][0];
      #pragma unroll
      for (int sk = 0; sk < 28; ++sk) {
        const int tap = sk >> 2, icb = (sk & 3)*16;
        const int t = nc + tap - 3;                 // conv3 input t
        const int tc = t < 0 ? 0 : (t > 9 ? 9 : t);
        const bool valid = (t >= 0) & (t <= 9);
        const int off = tc*72 + icb + kh8;
        half8 bh = *(const half8*)(bhp + off);
        half8 bl = *(const half8*)(blp + off);
        bh = valid ? bh : z8;
        bl = valid ? bl : z8;
        const half8 wh0 = *(const half8*)(sW + (size_t)(sk*2 + 0)*512 + lane*8);
        const half8 wh1 = *(const half8*)(sW + (size_t)(sk*2 + 1)*512 + lane*8);
        const half8 wl0 = *(const half8*)(sW + (size_t)(56 + sk*2)*512 + lane*8);
        const half8 wl1 = *(const half8*)(sW + (size_t)(57 + sk*2)*512 + lane*8);
        acc0 = mfma32(wh0, bh, acc0);
        acc0 = mfma32(wh0, bl, acc0);
        acc0 = mfma32(wl0, bh, acc0);
        acc1 = mfma32(wh1, bh, acc1);
        acc1 = mfma32(wh1, bl, acc1);
        acc1 = mfma32(wl1, bh, acc1);
      }
      auto epi = [&](const f32x16& ac, int ot) {
        #pragma unroll
        for (int q = 0; q < 4; ++q) {
          const int rowb = 8*q + rq + ot*32;
          const f32x4 sc = *(const f32x4*)(wsr + OFF_SC3 + rowb);
          const f32x4 sh = *(const f32x4*)(wsr + OFF_SH3 + rowb);
          f32x4 v;
          #pragma unroll
          for (int r = 0; r < 4; ++r) {
            float t2 = sc[r]*ac[4*q + r] + sh[r];
            t2 = t2 > 0.f ? t2 : 0.f;
            v[r] = (n < 10) ? t2 : 0.f;
          }
          #pragma unroll
          for (int r = 0; r < 4; ++r) {
            v[r] += __shfl_xor(v[r], 1, 16);
            v[r] += __shfl_xor(v[r], 2, 16);
            v[r] += __shfl_xor(v[r], 4, 16);
            v[r] += __shfl_xor(v[r], 8, 16);
          }
          if (n == 0)
            *(f32x4*)(sfp + (gbase + lbL)*64 + rowb) = v * 0.1f;
        }
      };
      epi(acc0, 0);
      epi(acc1, 1);
    }
    __syncthreads();   // protect sW + a1/a2 rewrite next iteration
  }
}

// ============================ RNN (16x16x16 MFMA, register-resident h) ============================
// One wave = 16 batches (columns). D[m=j_out][n=batch]; C/D row = (lane>>4)*4+reg
// equals B-operand k = (lane>>4)*4+j -> h feeds back with ZERO data movement.
// 3-term f16 split (A_hi*h_hi + A_hi*h_lo + A_lo*h_hi); x-drive computed in
// fp32 VALU and passed as the C operand.
__global__ __launch_bounds__(256) void rnn_kernel(
    const float* __restrict__ x, const float* __restrict__ wsr,
    const float* __restrict__ A, float* __restrict__ hout)
{
  const int lane = threadIdx.x & 63;
  const int wid = threadIdx.x >> 6;
  const int colb = lane & 15;            // batch column
  const int q = lane >> 4;               // quad: rows/k = q*4..q*4+3
  const size_t b = ((size_t)blockIdx.x*4 + wid)*16 + colb;

  // A' fragment: lane holds A[(lane&15)][q*4+j]  (m = j_out, k = i)
  const f32x4 av = *(const f32x4*)(A + (size_t)(lane & 15)*16 + q*4);
  half4 Ahi, Alo;
  #pragma unroll
  for (int j = 0; j < 4; ++j) {
    _Float16 hi = (_Float16)av[j];
    Ahi[j] = hi;
    Alo[j] = (_Float16)(av[j] - (float)hi);
  }
  // x-drive constants for this lane's 4 output rows j = q*4+r
  f32x4 pb0 = *(const f32x4*)(wsr + OFF_PB + 0*16 + q*4);
  f32x4 pb1 = *(const f32x4*)(wsr + OFF_PB + 1*16 + q*4);
  f32x4 pb2 = *(const f32x4*)(wsr + OFF_PB + 2*16 + q*4);
  f32x4 pb3 = *(const f32x4*)(wsr + OFF_PB + 3*16 + q*4);
  f32x4 pbb = *(const f32x4*)(wsr + OFF_PBB + q*4);

  const float* xb = x + b*400;
  half4 hh = {}, hl = {};
  f32x4 hf;
  #pragma unroll 2
  for (int t = 0; t < 100; ++t) {
    const f32x4 xv = *(const f32x4*)(xb + t*4);
    f32x4 U;
    #pragma unroll
    for (int r = 0; r < 4; ++r)
      U[r] = pbb[r] + xv[0]*pb0[r] + xv[1]*pb1[r] + xv[2]*pb2[r] + xv[3]*pb3[r];
    f32x4 u = mfma16(Alo, hh, U);
    u = mfma16(Ahi, hl, u);
    u = mfma16(Ahi, hh, u);
    #pragma unroll
    for (int r = 0; r < 4; ++r) {
      float e = __expf(2.f*u[r]);
      float hn = 1.f - 2.f/(e + 1.f);
      hf[r] = hn;
      _Float16 hi = (_Float16)hn;
      hh[r] = hi;
      hl[r] = (_Float16)(hn - (float)hi);
    }
  }
  *(f32x4*)(hout + b*16 + q*4) = hf;
}

// ============================ tail ============================
// lane = (b4 = lane>>4, og = lane&15): 4 batches/wave, o-quad per lane.
// All stage buffers are wave-private per (wid) -> no in-loop barriers.
__global__ __launch_bounds__(256) void tail_kernel(
    const float* __restrict__ wsr,
    const float* __restrict__ g1_w, const float* __restrict__ g1_b,
    const float* __restrict__ g2_w, const float* __restrict__ g2_b,
    const float* __restrict__ h1_w, const float* __restrict__ h1_b,
    const float* __restrict__ h2_w, const float* __restrict__ h2_b,
    const float* __restrict__ out_b, float* __restrict__ out)
{
  __shared__ float sG1[128*64];   // 32 KB, [k][o]
  __shared__ float sG2[64*64];    // 16 KB
  __shared__ float sH1[64*32];    // 8 KB
  __shared__ float sH2[32*3];
  __shared__ float sCO[16*64];    // 4 KB
  __shared__ float wbuf[16][132];
  __shared__ float tbuf[16][68];
  __shared__ float t2buf[16][36];
  __shared__ float hbuf[4][64];
  int tid = threadIdx.x;
  for (int i = tid; i < 128*64; i += 256) sG1[i] = g1_w[i];
  for (int i = tid; i < 64*64; i += 256) sG2[i] = g2_w[i];
  for (int i = tid; i < 64*32; i += 256) sH1[i] = h1_w[i];
  for (int i = tid; i < 96; i += 256) sH2[i] = h2_w[i];
  for (int i = tid; i < 16*64; i += 256) sCO[i] = wsr[OFF_CO + i];
  __syncthreads();

  const int lane = tid & 63, wid = tid >> 6;
  const int b4 = lane >> 4, og = lane & 15;
  const int wb = wid*4 + b4;
  const float* sf = wsr + OFF_SF;
  const float* hws = wsr + OFF_H;
  const f32x4 g1b4 = *(const f32x4*)(g1_b + 4*og);
  const f32x4 g2b4 = *(const f32x4*)(g2_b + 4*og);
  const f32x4 ob4  = *(const f32x4*)(out_b + 4*og);
  const f32x2 h1b2 = *(const f32x2*)(h1_b + 2*og);
  const float h2bv = (og < 3) ? h2_b[og] : 0.f;

  for (int seg = 0; seg < 4; ++seg) {
    const int wq = blockIdx.x*64 + seg*16 + wid*4;
    const int batch = wq + b4;
    hbuf[wid][lane] = hws[(size_t)wq*16 + lane];
    const f32x4 sfv = *(const f32x4*)(sf + (size_t)batch*64 + 4*og);
    f32x4 lcv = ob4;
    #pragma unroll
    for (int j = 0; j < 16; ++j) {
      const float hj = hbuf[wid][b4*16 + j];
      const f32x4 co = *(const f32x4*)(sCO + j*64 + 4*og);
      lcv += hj * co;
    }
    *(f32x4*)(&wbuf[wb][4*og]) = sfv;
    *(f32x4*)(&wbuf[wb][64 + 4*og]) = lcv;
    // L1: combined(128) @ g1 -> tanh
    f32x4 u = g1b4;
    #pragma unroll 8
    for (int k = 0; k < 128; ++k)
      u += wbuf[wb][k] * *(const f32x4*)(sG1 + k*64 + 4*og);
    f32x4 t1;
    #pragma unroll
    for (int r = 0; r < 4; ++r) {
      float e = __expf(2.f*u[r]);
      t1[r] = 1.f - 2.f/(e + 1.f);
    }
    *(f32x4*)(&tbuf[wb][4*og]) = t1;
    // L2: t1(64) @ g2 -> sigmoid -> gate
    f32x4 u2 = g2b4;
    #pragma unroll 8
    for (int k = 0; k < 64; ++k)
      u2 += tbuf[wb][k] * *(const f32x4*)(sG2 + k*64 + 4*og);
    f32x4 filt;
    #pragma unroll
    for (int r = 0; r < 4; ++r)
      filt[r] = sfv[r] / (1.f + __expf(-u2[r]));
    *(f32x4*)(&wbuf[wb][4*og]) = filt;
    // L3: filt(64) @ h1 -> relu (32 outs: 2 per lane)
    f32x2 r2 = h1b2;
    #pragma unroll 8
    for (int k = 0; k < 64; ++k)
      r2 += wbuf[wb][k] * *(const f32x2*)(sH1 + k*32 + 2*og);
    r2[0] = fmaxf(r2[0], 0.f); r2[1] = fmaxf(r2[1], 0.f);
    *(f32x2*)(&t2buf[wb][2*og]) = r2;
    // L4: (32) @ h2 -> 3 logits
    if (og < 3) {
      float a = h2bv;
      #pragma unroll
      for (int k = 0; k < 32; ++k) a += t2buf[wb][k] * sH2[k*3 + og];
      out[(size_t)batch*3 + og] = a;
    }
  }
}

// ============================ launch ============================
extern "C" void kernel_launch(void* const* d_in, const int* in_sizes, int n_in,
                              void* d_out, int out_size, void* d_ws, size_t ws_size,
                              hipStream_t stream) {
  const float* x       = (const float*)d_in[0];
  const float* conv1_w = (const float*)d_in[1];
  const float* conv1_b = (const float*)d_in[2];
  const float* conv2_w = (const float*)d_in[3];
  const float* conv2_b = (const float*)d_in[4];
  const float* conv3_w = (const float*)d_in[5];
  const float* conv3_b = (const float*)d_in[6];
  const float* bn1_g   = (const float*)d_in[7];
  const float* bn1_b   = (const float*)d_in[8];
  const float* bn2_g   = (const float*)d_in[9];
  const float* bn2_b   = (const float*)d_in[10];
  const float* bn3_g   = (const float*)d_in[11];
  const float* bn3_b   = (const float*)d_in[12];
  const float* proj_w  = (const float*)d_in[13];
  const float* proj_b  = (const float*)d_in[14];
  const float* A       = (const float*)d_in[15];
  const float* Bm      = (const float*)d_in[16];
  const float* Cm      = (const float*)d_in[17];
  const float* out_w   = (const float*)d_in[18];
  const float* out_b   = (const float*)d_in[19];
  const float* g1_w    = (const float*)d_in[20];
  const float* g1_b    = (const float*)d_in[21];
  const float* g2_w    = (const float*)d_in[22];
  const float* g2_b    = (const float*)d_in[23];
  const float* h1_w    = (const float*)d_in[24];
  const float* h1_b    = (const float*)d_in[25];
  const float* h2_w    = (const float*)d_in[26];
  const float* h2_b    = (const float*)d_in[27];
  float* ws = (float*)d_ws;
  float* out = (float*)d_out;

  prep_kernel<<<64, 256, 0, stream>>>(conv1_w, conv1_b, conv2_w, conv2_b,
      conv3_w, conv3_b, bn1_g, bn1_b, bn2_g, bn2_b, bn3_g, bn3_b,
      proj_w, proj_b, A, Bm, Cm, out_w, ws);
  conv_kernel<<<NB/(8*ITER), 256, 0, stream>>>(x, ws, ws + OFF_SF);
  rnn_kernel<<<NB/64, 256, 0, stream>>>(x, ws, A, ws + OFF_H);
  tail_kernel<<<NB/64, 256, 0, stream>>>(ws, g1_w, g1_b, g2_w, g2_b,
      h1_w, h1_b, h2_w, h2_b, out_b, out);
}

// Round 9
// 285.216 us; speedup vs baseline: 1.8543x; 1.1668x over previous
//
#include <hip/hip_runtime.h>
#include <cstddef>

#define NB 16384
#define ITER 4
#define TS 720    // act batch stride in halves (10 slots * 72)

typedef __attribute__((ext_vector_type(8))) _Float16 half8;
typedef __attribute__((ext_vector_type(4))) _Float16 half4;
typedef __attribute__((ext_vector_type(4))) float f32x4;
typedef __attribute__((ext_vector_type(2))) float f32x2;
typedef __attribute__((ext_vector_type(16))) float f32x16;

// ---- ws float offsets ----
#define OFF_W1T 0
#define OFF_SC1 768
#define OFF_SH1 832
#define OFF_SC2 896
#define OFF_SH2 960
#define OFF_SC3 1024
#define OFF_SH3 1088
#define OFF_PB  1152
#define OFF_PBB 1216
#define OFF_W2H 2304                   // w2 hi 10240 f, then lo 10240 f (contiguous)
#define OFF_W2L 12544
#define OFF_W3H 22784                  // w3 hi 14336 f, then lo 14336 f (contiguous)
#define OFF_W3L 37120
#define OFF_SF  51456                  // NB*64
#define OFF_H   (51456 + NB*64)        // NB*16 -> ends 1362176
#define OFF_TF  1362176                // tail frags: 31744 halves = 15872 floats
#define OFF_A2  1378048                // act2 global roundtrip (2 planes x NB*640 halves)
#define WS_NEED ((size_t)11863808 * 4) // bytes required for split-conv path

// tail frag half-offsets within OFF_TF region
#define G1H 0
#define G1L 8192
#define G2H 16384
#define G2L 20480
#define H1H 24576
#define H1L 26624
#define H2H 28672
#define H2L 29184
#define COH 29696
#define COL 30720
#define TFH 31744   // total halves

static __device__ __forceinline__ f32x16 mfma32(half8 a, half8 b, f32x16 c) {
  return __builtin_amdgcn_mfma_f32_32x32x16_f16(a, b, c, 0, 0, 0);
}
static __device__ __forceinline__ f32x4 mfma16(half4 a, half4 b, f32x4 c) {
  return __builtin_amdgcn_mfma_f32_16x16x16f16(a, b, c, 0, 0, 0);
}
static __device__ __forceinline__ f32x4 mfma16k32(half8 a, half8 b, f32x4 c) {
  return __builtin_amdgcn_mfma_f32_16x16x32_f16(a, b, c, 0, 0, 0);
}

// ============================ prep ============================
__global__ __launch_bounds__(256) void prep_kernel(
    const float* __restrict__ conv1_w, const float* __restrict__ conv1_b,
    const float* __restrict__ conv2_w, const float* __restrict__ conv2_b,
    const float* __restrict__ conv3_w, const float* __restrict__ conv3_b,
    const float* __restrict__ bn1_g, const float* __restrict__ bn1_b,
    const float* __restrict__ bn2_g, const float* __restrict__ bn2_b,
    const float* __restrict__ bn3_g, const float* __restrict__ bn3_b,
    const float* __restrict__ proj_w, const float* __restrict__ proj_b,
    const float* __restrict__ A, const float* __restrict__ Bm,
    const float* __restrict__ Cm, const float* __restrict__ out_w,
    const float* __restrict__ g1_w, const float* __restrict__ g2_w,
    const float* __restrict__ h1_w, const float* __restrict__ h2_w,
    float* __restrict__ ws)
{
  int tid = blockIdx.x * blockDim.x + threadIdx.x;
  int nt = gridDim.x * blockDim.x;
  const float s = rsqrtf(1.0f + 1e-5f);

  for (int i = tid; i < 64*12; i += nt) {
    int o = i & 63, rk = i >> 6;
    ws[OFF_W1T + i] = conv1_w[o*12 + rk];
  }
  for (int o = tid; o < 64; o += nt) {
    float s1 = bn1_g[o]*s, s2 = bn2_g[o]*s, s3 = bn3_g[o]*s;
    ws[OFF_SC1+o] = s1; ws[OFF_SH1+o] = s1*conv1_b[o] + bn1_b[o];
    ws[OFF_SC2+o] = s2; ws[OFF_SH2+o] = s2*conv2_b[o] + bn2_b[o];
    ws[OFF_SC3+o] = s3; ws[OFF_SH3+o] = s3*conv3_b[o] + bn3_b[o];
  }
  // conv2 A-fragments (32x32x16), hi/lo split
  {
    _Float16* w2h = (_Float16*)(ws + OFF_W2H);
    _Float16* w2l = (_Float16*)(ws + OFF_W2L);
    for (int i = tid; i < 20*2*64; i += nt) {
      int lane = i & 63, ot = (i >> 6) & 1, sk = i >> 7;
      int tap = sk >> 2, ic0 = (sk & 3)*16 + (lane >> 5)*8;
      int o = ot*32 + (lane & 31);
      #pragma unroll
      for (int j = 0; j < 8; ++j) {
        float w = conv2_w[o*320 + (ic0 + j)*5 + tap];
        _Float16 hi = (_Float16)w;
        w2h[(size_t)i*8 + j] = hi;
        w2l[(size_t)i*8 + j] = (_Float16)(w - (float)hi);
      }
    }
  }
  {
    _Float16* w3h = (_Float16*)(ws + OFF_W3H);
    _Float16* w3l = (_Float16*)(ws + OFF_W3L);
    for (int i = tid; i < 28*2*64; i += nt) {
      int lane = i & 63, ot = (i >> 6) & 1, sk = i >> 7;
      int tap = sk >> 2, ic0 = (sk & 3)*16 + (lane >> 5)*8;
      int o = ot*32 + (lane & 31);
      #pragma unroll
      for (int j = 0; j < 8; ++j) {
        float w = conv3_w[o*448 + (ic0 + j)*7 + tap];
        _Float16 hi = (_Float16)w;
        w3h[(size_t)i*8 + j] = hi;
        w3l[(size_t)i*8 + j] = (_Float16)(w - (float)hi);
      }
    }
  }
  // PB[c][j], PBB[j]
  for (int i = tid; i < 64; i += nt) {
    int c = i >> 4, j = i & 15;
    float acc = 0.f;
    for (int m = 0; m < 64; ++m) acc += proj_w[c*64+m]*Bm[m*16+j];
    ws[OFF_PB + i] = acc;
  }
  for (int j = tid; j < 16; j += nt) {
    float acc = 0.f;
    for (int m = 0; m < 64; ++m) acc += proj_b[m]*Bm[m*16+j];
    ws[OFF_PBB + j] = acc;
  }

  // ---- tail MFMA fragments (hi/lo) ----
  _Float16* tf = (_Float16*)(ws + OFF_TF);
  // g1: 16x16x32, frag f = mt*4+ks; A[m=o][k] = g1_w[k*64+o]
  for (int i = tid; i < 16*64; i += nt) {
    int l = i & 63, f = i >> 6, mt = f >> 2, ks = f & 3;
    int o = mt*16 + (l & 15), kb = ks*32 + (l >> 4)*8;
    #pragma unroll
    for (int j = 0; j < 8; ++j) {
      float w = g1_w[(size_t)(kb + j)*64 + o];
      _Float16 hi = (_Float16)w;
      tf[G1H + (size_t)i*8 + j] = hi;
      tf[G1L + (size_t)i*8 + j] = (_Float16)(w - (float)hi);
    }
  }
  // g2: frag f = mt*2+ks (mt 0..3, ks 0..1)
  for (int i = tid; i < 8*64; i += nt) {
    int l = i & 63, f = i >> 6, mt = f >> 1, ks = f & 1;
    int o = mt*16 + (l & 15), kb = ks*32 + (l >> 4)*8;
    #pragma unroll
    for (int j = 0; j < 8; ++j) {
      float w = g2_w[(size_t)(kb + j)*64 + o];
      _Float16 hi = (_Float16)w;
      tf[G2H + (size_t)i*8 + j] = hi;
      tf[G2L + (size_t)i*8 + j] = (_Float16)(w - (float)hi);
    }
  }
  // h1: frag f = mt*2+ks (mt 0..1, ks 0..1); A[m=h][k] = h1_w[k*32+h]
  for (int i = tid; i < 4*64; i += nt) {
    int l = i & 63, f = i >> 6, mt = f >> 1, ks = f & 1;
    int hx = mt*16 + (l & 15), kb = ks*32 + (l >> 4)*8;
    #pragma unroll
    for (int j = 0; j < 8; ++j) {
      float w = h1_w[(size_t)(kb + j)*32 + hx];
      _Float16 hi = (_Float16)w;
      tf[H1H + (size_t)i*8 + j] = hi;
      tf[H1L + (size_t)i*8 + j] = (_Float16)(w - (float)hi);
    }
  }
  // h2: 1 frag; A[m][k] = (m<3)? h2_w[k*3+m] : 0
  for (int i = tid; i < 64; i += nt) {
    int l = i, m = l & 15, kb = (l >> 4)*8;
    #pragma unroll
    for (int j = 0; j < 8; ++j) {
      float w = (m < 3) ? h2_w[(size_t)(kb + j)*3 + m] : 0.f;
      _Float16 hi = (_Float16)w;
      tf[H2H + (size_t)i*8 + j] = hi;
      tf[H2L + (size_t)i*8 + j] = (_Float16)(w - (float)hi);
    }
  }
  // CO: 16x16x16, frag f = mt; A[m=o][k=j'] = CO[j'][o] = sum_m Cm[j'][m]*out_w[m][o]
  for (int i = tid; i < 4*64; i += nt) {
    int l = i & 63, mt = i >> 6;
    int o = mt*16 + (l & 15), kb = (l >> 4)*4;
    #pragma unroll
    for (int j = 0; j < 4; ++j) {
      float acc = 0.f;
      for (int m = 0; m < 64; ++m) acc += Cm[(kb + j)*64 + m]*out_w[m*64 + o];
      _Float16 hi = (_Float16)acc;
      tf[COH + (size_t)i*4 + j] = hi;
      tf[COL + (size_t)i*4 + j] = (_Float16)(acc - (float)hi);
    }
  }
}

// ============================ conv12 (split path) ============================
// 512 thr = 8 waves; wave w = batches 2w,2w+1; 16 batches/block; grid NB/16.
// LDS: w2 hi+lo 80 KB + a1 h/l 45 KB = 125 KB -> 8 waves = 2/SIMD.
__global__ __launch_bounds__(512) void conv12_kernel(
    const float* __restrict__ x, const float* __restrict__ wsr,
    _Float16* __restrict__ a2gh, _Float16* __restrict__ a2gl)
{
  __shared__ __align__(16) _Float16 sW[40960];
  __shared__ __align__(16) _Float16 a1h[16][TS], a1l[16][TS];

  const int tid = threadIdx.x;
  const int lane = tid & 63;
  const int wid = tid >> 6;
  const int n = lane & 15;
  const int nc = (n < 10) ? n : 9;
  const int kh8 = (lane >> 5) * 8;
  const int rq = 4 * (lane >> 5);
  const int lbL = 2*wid + ((lane >> 4) & 1);
  const half8 z8 = {};
  const size_t B0g = (size_t)blockIdx.x * 16;

  { // stage w2 hi+lo (contiguous in ws)
    const f32x4* src = (const f32x4*)(wsr + OFF_W2H);
    f32x4* dst = (f32x4*)sW;
    for (int i = tid; i < 5120; i += 512) dst[i] = src[i];
  }
  // conv1 for this wave's 2 batches
  {
    const float sc1 = wsr[OFF_SC1 + lane], sh1 = wsr[OFF_SH1 + lane];
    #pragma unroll
    for (int bb = 0; bb < 2; ++bb) {
      const int lb = 2*wid + bb;
      const size_t gb = B0g + lb;
      float xv[4][12];
      #pragma unroll
      for (int c = 0; c < 4; ++c) { xv[c][0] = 0.f; xv[c][11] = 0.f; }
      #pragma unroll
      for (int tt = 0; tt < 10; ++tt)
        #pragma unroll
        for (int c = 0; c < 4; ++c)
          xv[c][1 + tt] = x[gb*400 + (90 + tt)*4 + c];
      float a1[10];
      #pragma unroll
      for (int t = 0; t < 10; ++t) a1[t] = 0.f;
      #pragma unroll
      for (int c = 0; c < 4; ++c)
        #pragma unroll
        for (int k = 0; k < 3; ++k) {
          const float wv = wsr[OFF_W1T + (c*3 + k)*64 + lane];
          #pragma unroll
          for (int t = 0; t < 10; ++t) a1[t] += wv * xv[c][t + k];
        }
      #pragma unroll
      for (int t = 0; t < 10; ++t) {
        float v = sc1*a1[t] + sh1;
        v = v > 0.f ? v : 0.f;
        _Float16 hi = (_Float16)v;
        a1h[lb][t*72 + lane] = hi;
        a1l[lb][t*72 + lane] = (_Float16)(v - (float)hi);
      }
    }
  }
  __syncthreads();

  // conv2 (both otiles)
  {
    f32x16 acc0, acc1;
    #pragma unroll
    for (int r = 0; r < 16; ++r) { acc0[r] = 0.f; acc1[r] = 0.f; }
    const _Float16* bhp = &a1h[lbL][0];
    const _Float16* blp = &a1l[lbL][0];
    #pragma unroll
    for (int sk = 0; sk < 20; ++sk) {
      const int tap = sk >> 2, icb = (sk & 3)*16;
      const int t = nc + tap - 2;
      const int tc = t < 0 ? 0 : (t > 9 ? 9 : t);
      const bool valid = (t >= 0) & (t <= 9);
      const int off = tc*72 + icb + kh8;
      half8 bh = *(const half8*)(bhp + off);
      half8 bl = *(const half8*)(blp + off);
      bh = valid ? bh : z8;
      bl = valid ? bl : z8;
      const half8 wh0 = *(const half8*)(sW + (size_t)(sk*2 + 0)*512 + lane*8);
      const half8 wh1 = *(const half8*)(sW + (size_t)(sk*2 + 1)*512 + lane*8);
      const half8 wl0 = *(const half8*)(sW + (size_t)(40 + sk*2)*512 + lane*8);
      const half8 wl1 = *(const half8*)(sW + (size_t)(41 + sk*2)*512 + lane*8);
      acc0 = mfma32(wh0, bh, acc0);
      acc0 = mfma32(wh0, bl, acc0);
      acc0 = mfma32(wl0, bh, acc0);
      acc1 = mfma32(wh1, bh, acc1);
      acc1 = mfma32(wh1, bl, acc1);
      acc1 = mfma32(wl1, bh, acc1);
    }
    if (n < 10) {
      const size_t gb = B0g + lbL;
      auto epi = [&](const f32x16& ac, int ot) {
        #pragma unroll
        for (int q = 0; q < 4; ++q) {
          const int rowb = 8*q + rq + ot*32;
          const f32x4 sc = *(const f32x4*)(wsr + OFF_SC2 + rowb);
          const f32x4 sh = *(const f32x4*)(wsr + OFF_SH2 + rowb);
          half4 h4, l4;
          #pragma unroll
          for (int r = 0; r < 4; ++r) {
            float v = sc[r]*ac[4*q + r] + sh[r];
            v = v > 0.f ? v : 0.f;
            _Float16 hi = (_Float16)v;
            h4[r] = hi;
            l4[r] = (_Float16)(v - (float)hi);
          }
          *(half4*)(a2gh + gb*640 + n*64 + rowb) = h4;
          *(half4*)(a2gl + gb*640 + n*64 + rowb) = l4;
        }
      };
      epi(acc0, 0);
      epi(acc1, 1);
    }
  }
}

// ============================ conv3 (split path) ============================
// 512 thr = 8 waves; wave w = pair (batches 2w,2w+1); grid NB/16.
// LDS: w3 hi+lo 112 KB + a2 h/l 45 KB = 157 KB.
__global__ __launch_bounds__(512) void conv3k_kernel(
    const float* __restrict__ wsr,
    const _Float16* __restrict__ a2gh, const _Float16* __restrict__ a2gl,
    float* __restrict__ sfp)
{
  __shared__ __align__(16) _Float16 sW[57344];
  __shared__ __align__(16) _Float16 a2h[16][TS], a2l[16][TS];

  const int tid = threadIdx.x;
  const int lane = tid & 63;
  const int wid = tid >> 6;
  const int n = lane & 15;
  const int nc = (n < 10) ? n : 9;
  const int kh8 = (lane >> 5) * 8;
  const int rq = 4 * (lane >> 5);
  const int lbL = 2*wid + ((lane >> 4) & 1);
  const half8 z8 = {};
  const size_t B0g = (size_t)blockIdx.x * 16;

  { // stage w3 hi+lo
    const f32x4* src = (const f32x4*)(wsr + OFF_W3H);
    f32x4* dst = (f32x4*)sW;
    for (int i = tid; i < 7168; i += 512) dst[i] = src[i];
  }
  { // stage a2 from global: 16 batches x 640 halves x 2 planes
    for (int i = tid; i < 1280; i += 512) {
      int idx = i*8;
      int lb = idx / 640, rem = idx % 640;
      int t = rem >> 6, o = rem & 63;
      *(half8*)(&a2h[lb][t*72 + o]) = *(const half8*)(a2gh + (B0g + lb)*640 + rem);
      *(half8*)(&a2l[lb][t*72 + o]) = *(const half8*)(a2gl + (B0g + lb)*640 + rem);
    }
  }
  __syncthreads();

  {
    f32x16 acc0, acc1;
    #pragma unroll
    for (int r = 0; r < 16; ++r) { acc0[r] = 0.f; acc1[r] = 0.f; }
    const _Float16* bhp = &a2h[lbL][0];
    const _Float16* blp = &a2l[lbL][0];
    #pragma unroll
    for (int sk = 0; sk < 28; ++sk) {
      const int tap = sk >> 2, icb = (sk & 3)*16;
      const int t = nc + tap - 3;
      const int tc = t < 0 ? 0 : (t > 9 ? 9 : t);
      const bool valid = (t >= 0) & (t <= 9);
      const int off = tc*72 + icb + kh8;
      half8 bh = *(const half8*)(bhp + off);
      half8 bl = *(const half8*)(blp + off);
      bh = valid ? bh : z8;
      bl = valid ? bl : z8;
      const half8 wh0 = *(const half8*)(sW + (size_t)(sk*2 + 0)*512 + lane*8);
      const half8 wh1 = *(const half8*)(sW + (size_t)(sk*2 + 1)*512 + lane*8);
      const half8 wl0 = *(const half8*)(sW + (size_t)(56 + sk*2)*512 + lane*8);
      const half8 wl1 = *(const half8*)(sW + (size_t)(57 + sk*2)*512 + lane*8);
      acc0 = mfma32(wh0, bh, acc0);
      acc0 = mfma32(wh0, bl, acc0);
      acc0 = mfma32(wl0, bh, acc0);
      acc1 = mfma32(wh1, bh, acc1);
      acc1 = mfma32(wh1, bl, acc1);
      acc1 = mfma32(wl1, bh, acc1);
    }
    auto epi = [&](const f32x16& ac, int ot) {
      #pragma unroll
      for (int q = 0; q < 4; ++q) {
        const int rowb = 8*q + rq + ot*32;
        const f32x4 sc = *(const f32x4*)(wsr + OFF_SC3 + rowb);
        const f32x4 sh = *(const f32x4*)(wsr + OFF_SH3 + rowb);
        f32x4 v;
        #pragma unroll
        for (int r = 0; r < 4; ++r) {
          float t2 = sc[r]*ac[4*q + r] + sh[r];
          t2 = t2 > 0.f ? t2 : 0.f;
          v[r] = (n < 10) ? t2 : 0.f;
        }
        #pragma unroll
        for (int r = 0; r < 4; ++r) {
          v[r] += __shfl_xor(v[r], 1, 16);
          v[r] += __shfl_xor(v[r], 2, 16);
          v[r] += __shfl_xor(v[r], 4, 16);
          v[r] += __shfl_xor(v[r], 8, 16);
        }
        if (n == 0)
          *(f32x4*)(sfp + (B0g + lbL)*64 + rowb) = v * 0.1f;
      }
    };
    epi(acc0, 0);
    epi(acc1, 1);
  }
}

// ============================ conv (fallback: single kernel, r8) ============================
__global__ __launch_bounds__(256) void conv_kernel(
    const float* __restrict__ x, const float* __restrict__ wsr,
    float* __restrict__ sfp)
{
  __shared__ __align__(16) _Float16 sW[57344];
  __shared__ __align__(16) _Float16 a1h[8][TS], a1l[8][TS];
  __shared__ __align__(16) _Float16 a2h[8][TS], a2l[8][TS];

  const int tid = threadIdx.x;
  const int lane = tid & 63;
  const int wid = tid >> 6;
  const int n = lane & 15;
  const int nc = (n < 10) ? n : 9;
  const int kh8 = (lane >> 5) * 8;
  const int rq = 4 * (lane >> 5);
  const int lb0 = (wid >> 1)*4 + (wid & 1)*2;
  const int lbL = lb0 + ((lane >> 4) & 1);
  const half8 z8 = {};
  const float sc1 = wsr[OFF_SC1 + lane], sh1 = wsr[OFF_SH1 + lane];

  for (int it = 0; it < ITER; ++it) {
    const size_t gbase = (size_t)blockIdx.x*(8*ITER) + (size_t)it*8;
    {
      const f32x4* src = (const f32x4*)(wsr + OFF_W2H);
      f32x4* dst = (f32x4*)sW;
      for (int i = tid; i < 5120; i += 256) dst[i] = src[i];
    }
    #pragma unroll
    for (int bb = 0; bb < 2; ++bb) {
      const int lb = lb0 + bb;
      const size_t gb = gbase + lb;
      float xv[4][12];
      #pragma unroll
      for (int c = 0; c < 4; ++c) { xv[c][0] = 0.f; xv[c][11] = 0.f; }
      #pragma unroll
      for (int tt = 0; tt < 10; ++tt)
        #pragma unroll
        for (int c = 0; c < 4; ++c)
          xv[c][1 + tt] = x[gb*400 + (90 + tt)*4 + c];
      float a1[10];
      #pragma unroll
      for (int t = 0; t < 10; ++t) a1[t] = 0.f;
      #pragma unroll
      for (int c = 0; c < 4; ++c)
        #pragma unroll
        for (int k = 0; k < 3; ++k) {
          const float wv = wsr[OFF_W1T + (c*3 + k)*64 + lane];
          #pragma unroll
          for (int t = 0; t < 10; ++t) a1[t] += wv * xv[c][t + k];
        }
      #pragma unroll
      for (int t = 0; t < 10; ++t) {
        float v = sc1*a1[t] + sh1;
        v = v > 0.f ? v : 0.f;
        _Float16 hi = (_Float16)v;
        a1h[lb][t*72 + lane] = hi;
        a1l[lb][t*72 + lane] = (_Float16)(v - (float)hi);
      }
    }
    __syncthreads();
    {
      f32x16 acc0, acc1;
      #pragma unroll
      for (int r = 0; r < 16; ++r) { acc0[r] = 0.f; acc1[r] = 0.f; }
      const _Float16* bhp = &a1h[lbL][0];
      const _Float16* blp = &a1l[lbL][0];
      #pragma unroll
      for (int sk = 0; sk < 20; ++sk) {
        const int tap = sk >> 2, icb = (sk & 3)*16;
        const int t = nc + tap - 2;
        const int tc = t < 0 ? 0 : (t > 9 ? 9 : t);
        const bool valid = (t >= 0) & (t <= 9);
        const int off = tc*72 + icb + kh8;
        half8 bh = *(const half8*)(bhp + off);
        half8 bl = *(const half8*)(blp + off);
        bh = valid ? bh : z8;
        bl = valid ? bl : z8;
        const half8 wh0 = *(const half8*)(sW + (size_t)(sk*2 + 0)*512 + lane*8);
        const half8 wh1 = *(const half8*)(sW + (size_t)(sk*2 + 1)*512 + lane*8);
        const half8 wl0 = *(const half8*)(sW + (size_t)(40 + sk*2)*512 + lane*8);
        const half8 wl1 = *(const half8*)(sW + (size_t)(41 + sk*2)*512 + lane*8);
        acc0 = mfma32(wh0, bh, acc0);
        acc0 = mfma32(wh0, bl, acc0);
        acc0 = mfma32(wl0, bh, acc0);
        acc1 = mfma32(wh1, bh, acc1);
        acc1 = mfma32(wh1, bl, acc1);
        acc1 = mfma32(wl1, bh, acc1);
      }
      if (n < 10) {
        auto epi = [&](const f32x16& ac, int ot) {
          #pragma unroll
          for (int q = 0; q < 4; ++q) {
            const int rowb = 8*q + rq + ot*32;
            const f32x4 sc = *(const f32x4*)(wsr + OFF_SC2 + rowb);
            const f32x4 sh = *(const f32x4*)(wsr + OFF_SH2 + rowb);
            half4 h4, l4;
            #pragma unroll
            for (int r = 0; r < 4; ++r) {
              float v = sc[r]*ac[4*q + r] + sh[r];
              v = v > 0.f ? v : 0.f;
              _Float16 hi = (_Float16)v;
              h4[r] = hi;
              l4[r] = (_Float16)(v - (float)hi);
            }
            *(half4*)(&a2h[lbL][n*72 + rowb]) = h4;
            *(half4*)(&a2l[lbL][n*72 + rowb]) = l4;
          }
        };
        epi(acc0, 0);
        epi(acc1, 1);
      }
    }
    __syncthreads();
    {
      const f32x4* src = (const f32x4*)(wsr + OFF_W3H);
      f32x4* dst = (f32x4*)sW;
      for (int i = tid; i < 7168; i += 256) dst[i] = src[i];
    }
    __syncthreads();
    {
      f32x16 acc0, acc1;
      #pragma unroll
      for (int r = 0; r < 16; ++r) { acc0[r] = 0.f; acc1[r] = 0.f; }
      const _Float16* bhp = &a2h[lbL][0];
      const _Float16* blp = &a2l[lbL][0];
      #pragma unroll
      for (int sk = 0; sk < 28; ++sk) {
        const int tap = sk >> 2, icb = (sk & 3)*16;
        const int t = nc + tap - 3;
        const int tc = t < 0 ? 0 : (t > 9 ? 9 : t);
        const bool valid = (t >= 0) & (t <= 9);
        const int off = tc*72 + icb + kh8;
        half8 bh = *(const half8*)(bhp + off);
        half8 bl = *(const half8*)(blp + off);
        bh = valid ? bh : z8;
        bl = valid ? bl : z8;
        const half8 wh0 = *(const half8*)(sW + (size_t)(sk*2 + 0)*512 + lane*8);
        const half8 wh1 = *(const half8*)(sW + (size_t)(sk*2 + 1)*512 + lane*8);
        const half8 wl0 = *(const half8*)(sW + (size_t)(56 + sk*2)*512 + lane*8);
        const half8 wl1 = *(const half8*)(sW + (size_t)(57 + sk*2)*512 + lane*8);
        acc0 = mfma32(wh0, bh, acc0);
        acc0 = mfma32(wh0, bl, acc0);
        acc0 = mfma32(wl0, bh, acc0);
        acc1 = mfma32(wh1, bh, acc1);
        acc1 = mfma32(wh1, bl, acc1);
        acc1 = mfma32(wl1, bh, acc1);
      }
      auto epi = [&](const f32x16& ac, int ot) {
        #pragma unroll
        for (int q = 0; q < 4; ++q) {
          const int rowb = 8*q + rq + ot*32;
          const f32x4 sc = *(const f32x4*)(wsr + OFF_SC3 + rowb);
          const f32x4 sh = *(const f32x4*)(wsr + OFF_SH3 + rowb);
          f32x4 v;
          #pragma unroll
          for (int r = 0; r < 4; ++r) {
            float t2 = sc[r]*ac[4*q + r] + sh[r];
            t2 = t2 > 0.f ? t2 : 0.f;
            v[r] = (n < 10) ? t2 : 0.f;
          }
          #pragma unroll
          for (int r = 0; r < 4; ++r) {
            v[r] += __shfl_xor(v[r], 1, 16);
            v[r] += __shfl_xor(v[r], 2, 16);
            v[r] += __shfl_xor(v[r], 4, 16);
            v[r] += __shfl_xor(v[r], 8, 16);
          }
          if (n == 0)
            *(f32x4*)(sfp + (gbase + lbL)*64 + rowb) = v * 0.1f;
        }
      };
      epi(acc0, 0);
      epi(acc1, 1);
    }
    __syncthreads();
  }
}

// ============================ RNN (unchanged, verified) ============================
__global__ __launch_bounds__(256) void rnn_kernel(
    const float* __restrict__ x, const float* __restrict__ wsr,
    const float* __restrict__ A, float* __restrict__ hout)
{
  const int lane = threadIdx.x & 63;
  const int wid = threadIdx.x >> 6;
  const int colb = lane & 15;
  const int q = lane >> 4;
  const size_t b = ((size_t)blockIdx.x*4 + wid)*16 + colb;

  const f32x4 av = *(const f32x4*)(A + (size_t)(lane & 15)*16 + q*4);
  half4 Ahi, Alo;
  #pragma unroll
  for (int j = 0; j < 4; ++j) {
    _Float16 hi = (_Float16)av[j];
    Ahi[j] = hi;
    Alo[j] = (_Float16)(av[j] - (float)hi);
  }
  f32x4 pb0 = *(const f32x4*)(wsr + OFF_PB + 0*16 + q*4);
  f32x4 pb1 = *(const f32x4*)(wsr + OFF_PB + 1*16 + q*4);
  f32x4 pb2 = *(const f32x4*)(wsr + OFF_PB + 2*16 + q*4);
  f32x4 pb3 = *(const f32x4*)(wsr + OFF_PB + 3*16 + q*4);
  f32x4 pbb = *(const f32x4*)(wsr + OFF_PBB + q*4);

  const float* xb = x + b*400;
  half4 hh = {}, hl = {};
  f32x4 hf;
  #pragma unroll 2
  for (int t = 0; t < 100; ++t) {
    const f32x4 xv = *(const f32x4*)(xb + t*4);
    f32x4 U;
    #pragma unroll
    for (int r = 0; r < 4; ++r)
      U[r] = pbb[r] + xv[0]*pb0[r] + xv[1]*pb1[r] + xv[2]*pb2[r] + xv[3]*pb3[r];
    f32x4 u = mfma16(Alo, hh, U);
    u = mfma16(Ahi, hl, u);
    u = mfma16(Ahi, hh, u);
    #pragma unroll
    for (int r = 0; r < 4; ++r) {
      float e = __expf(2.f*u[r]);
      float hn = 1.f - 2.f/(e + 1.f);
      hf[r] = hn;
      _Float16 hi = (_Float16)hn;
      hh[r] = hi;
      hl[r] = (_Float16)(hn - (float)hi);
    }
  }
  *(f32x4*)(hout + b*16 + q*4) = hf;
}

// ============================ tail (MFMA, 16 batches/wave) ============================
// Per-wave act areas (halves within sAct + wid*10240):
#define CMBH 0
#define CMBL 2176
#define T1H  4352
#define T1L  5504
#define FLH  6656
#define FLL  7808
#define RH   8960
#define RL   9600
__global__ __launch_bounds__(256) void tail_kernel(
    const float* __restrict__ wsr,
    const float* __restrict__ g1_b, const float* __restrict__ g2_b,
    const float* __restrict__ h1_b, const float* __restrict__ h2_b,
    const float* __restrict__ out_b, float* __restrict__ out)
{
  __shared__ __align__(16) _Float16 sWF[TFH];       // 62 KB weight frags
  __shared__ __align__(16) _Float16 sAct[4*10240];  // 80 KB act staging

  const int tid = threadIdx.x;
  const int lane = tid & 63;
  const int wid = tid >> 6;
  const int n = lane & 15;
  const int q = lane >> 4;
  const int B0 = blockIdx.x*64 + wid*16;

  { // stage weight frags (contiguous image in ws)
    const f32x4* src = (const f32x4*)(wsr + OFF_TF);
    f32x4* dst = (f32x4*)sWF;
    for (int i = tid; i < TFH/8; i += 256) dst[i] = src[i];
  }
  __syncthreads();

  _Float16* wa = sAct + wid*10240;
  const float* sf = wsr + OFF_SF;
  const float* hws = wsr + OFF_H;

  // ---- lc = out_b + h @ CO (16x16x16, 3-term) ----
  const f32x4 hv = *(const f32x4*)(hws + (size_t)(B0 + n)*16 + q*4);
  half4 hh, hl;
  #pragma unroll
  for (int j = 0; j < 4; ++j) {
    _Float16 hi = (_Float16)hv[j];
    hh[j] = hi;
    hl[j] = (_Float16)(hv[j] - (float)hi);
  }
  f32x4 lc[4];
  #pragma unroll
  for (int mt = 0; mt < 4; ++mt) {
    lc[mt] = *(const f32x4*)(out_b + mt*16 + q*4);
    const half4 ah = *(const half4*)(sWF + COH + (size_t)(mt*64 + lane)*4);
    const half4 al = *(const half4*)(sWF + COL + (size_t)(mt*64 + lane)*4);
    lc[mt] = mfma16(al, hh, lc[mt]);
    lc[mt] = mfma16(ah, hl, lc[mt]);
    lc[mt] = mfma16(ah, hh, lc[mt]);
  }
  // ---- stage combined[b][k] (k<64 = sf, k>=64 = lc), hi/lo ----
  f32x4 sfv[4];
  #pragma unroll
  for (int mt = 0; mt < 4; ++mt) {
    sfv[mt] = *(const f32x4*)(sf + (size_t)(B0 + n)*64 + mt*16 + q*4);
    half4 sh4, sl4, lh4, ll4;
    #pragma unroll
    for (int r = 0; r < 4; ++r) {
      _Float16 hi = (_Float16)sfv[mt][r];
      sh4[r] = hi; sl4[r] = (_Float16)(sfv[mt][r] - (float)hi);
      _Float16 hi2 = (_Float16)lc[mt][r];
      lh4[r] = hi2; ll4[r] = (_Float16)(lc[mt][r] - (float)hi2);
    }
    *(half4*)(wa + CMBH + n*136 + mt*16 + q*4) = sh4;
    *(half4*)(wa + CMBL + n*136 + mt*16 + q*4) = sl4;
    *(half4*)(wa + CMBH + n*136 + 64 + mt*16 + q*4) = lh4;
    *(half4*)(wa + CMBL + n*136 + 64 + mt*16 + q*4) = ll4;
  }
  // ---- L1: combined(128) @ g1 -> tanh ----
  f32x4 u1[4];
  #pragma unroll
  for (int mt = 0; mt < 4; ++mt) u1[mt] = *(const f32x4*)(g1_b + mt*16 + q*4);
  #pragma unroll
  for (int ks = 0; ks < 4; ++ks) {
    const half8 bh = *(const half8*)(wa + CMBH + n*136 + ks*32 + q*8);
    const half8 bl = *(const half8*)(wa + CMBL + n*136 + ks*32 + q*8);
    #pragma unroll
    for (int mt = 0; mt < 4; ++mt) {
      const half8 ah = *(const half8*)(sWF + G1H + (size_t)((mt*4 + ks)*64 + lane)*8);
      const half8 al = *(const half8*)(sWF + G1L + (size_t)((mt*4 + ks)*64 + lane)*8);
      u1[mt] = mfma16k32(al, bh, u1[mt]);
      u1[mt] = mfma16k32(ah, bl, u1[mt]);
      u1[mt] = mfma16k32(ah, bh, u1[mt]);
    }
  }
  #pragma unroll
  for (int mt = 0; mt < 4; ++mt) {
    half4 th4, tl4;
    #pragma unroll
    for (int r = 0; r < 4; ++r) {
      float e = __expf(2.f*u1[mt][r]);
      float t1 = 1.f - 2.f/(e + 1.f);
      _Float16 hi = (_Float16)t1;
      th4[r] = hi; tl4[r] = (_Float16)(t1 - (float)hi);
    }
    *(half4*)(wa + T1H + n*72 + mt*16 + q*4) = th4;
    *(half4*)(wa + T1L + n*72 + mt*16 + q*4) = tl4;
  }
  // ---- L2: t1(64) @ g2 -> sigmoid -> filt ----
  f32x4 u2[4];
  #pragma unroll
  for (int mt = 0; mt < 4; ++mt) u2[mt] = *(const f32x4*)(g2_b + mt*16 + q*4);
  #pragma unroll
  for (int ks = 0; ks < 2; ++ks) {
    const half8 bh = *(const half8*)(wa + T1H + n*72 + ks*32 + q*8);
    const half8 bl = *(const half8*)(wa + T1L + n*72 + ks*32 + q*8);
    #pragma unroll
    for (int mt = 0; mt < 4; ++mt) {
      const half8 ah = *(const half8*)(sWF + G2H + (size_t)((mt*2 + ks)*64 + lane)*8);
      const half8 al = *(const half8*)(sWF + G2L + (size_t)((mt*2 + ks)*64 + lane)*8);
      u2[mt] = mfma16k32(al, bh, u2[mt]);
      u2[mt] = mfma16k32(ah, bl, u2[mt]);
      u2[mt] = mfma16k32(ah, bh, u2[mt]);
    }
  }
  #pragma unroll
  for (int mt = 0; mt < 4; ++mt) {
    half4 fh4, fl4;
    #pragma unroll
    for (int r = 0; r < 4; ++r) {
      float gate = 1.f/(1.f + __expf(-u2[mt][r]));
      float f = sfv[mt][r] * gate;
      _Float16 hi = (_Float16)f;
      fh4[r] = hi; fl4[r] = (_Float16)(f - (float)hi);
    }
    *(half4*)(wa + FLH + n*72 + mt*16 + q*4) = fh4;
    *(half4*)(wa + FLL + n*72 + mt*16 + q*4) = fl4;
  }
  // ---- L3: filt(64) @ h1 -> relu ----
  f32x4 u3[2];
  #pragma unroll
  for (int mt = 0; mt < 2; ++mt) u3[mt] = *(const f32x4*)(h1_b + mt*16 + q*4);
  #pragma unroll
  for (int ks = 0; ks < 2; ++ks) {
    const half8 bh = *(const half8*)(wa + FLH + n*72 + ks*32 + q*8);
    const half8 bl = *(const half8*)(wa + FLL + n*72 + ks*32 + q*8);
    #pragma unroll
    for (int mt = 0; mt < 2; ++mt) {
      const half8 ah = *(const half8*)(sWF + H1H + (size_t)((mt*2 + ks)*64 + lane)*8);
      const half8 al = *(const half8*)(sWF + H1L + (size_t)((mt*2 + ks)*64 + lane)*8);
      u3[mt] = mfma16k32(al, bh, u3[mt]);
      u3[mt] = mfma16k32(ah, bl, u3[mt]);
      u3[mt] = mfma16k32(ah, bh, u3[mt]);
    }
  }
  #pragma unroll
  for (int mt = 0; mt < 2; ++mt) {
    half4 rh4, rl4;
    #pragma unroll
    for (int r = 0; r < 4; ++r) {
      float v = fmaxf(u3[mt][r], 0.f);
      _Float16 hi = (_Float16)v;
      rh4[r] = hi; rl4[r] = (_Float16)(v - (float)hi);
    }
    *(half4*)(wa + RH + n*40 + mt*16 + q*4) = rh4;
    *(half4*)(wa + RL + n*40 + mt*16 + q*4) = rl4;
  }
  // ---- L4: r(32) @ h2 -> 3 logits ----
  {
    f32x4 u4;
    if (q == 0) { u4[0] = h2_b[0]; u4[1] = h2_b[1]; u4[2] = h2_b[2]; u4[3] = 0.f; }
    else { u4[0] = 0.f; u4[1] = 0.f; u4[2] = 0.f; u4[3] = 0.f; }
    const half8 bh = *(const half8*)(wa + RH + n*40 + q*8);
    const half8 bl = *(const half8*)(wa + RL + n*40 + q*8);
    const half8 ah = *(const half8*)(sWF + H2H + (size_t)lane*8);
    const half8 al = *(const half8*)(sWF + H2L + (size_t)lane*8);
    u4 = mfma16k32(al, bh, u4);
    u4 = mfma16k32(ah, bl, u4);
    u4 = mfma16k32(ah, bh, u4);
    if (q == 0) {
      out[(size_t)(B0 + n)*3 + 0] = u4[0];
      out[(size_t)(B0 + n)*3 + 1] = u4[1];
      out[(size_t)(B0 + n)*3 + 2] = u4[2];
    }
  }
}

// ============================ launch ============================
extern "C" void kernel_launch(void* const* d_in, const int* in_sizes, int n_in,
                              void* d_out, int out_size, void* d_ws, size_t ws_size,
                              hipStream_t stream) {
  const float* x       = (const float*)d_in[0];
  const float* conv1_w = (const float*)d_in[1];
  const float* conv1_b = (const float*)d_in[2];
  const float* conv2_w = (const float*)d_in[3];
  const float* conv2_b = (const float*)d_in[4];
  const float* conv3_w = (const float*)d_in[5];
  const float* conv3_b = (const float*)d_in[6];
  const float* bn1_g   = (const float*)d_in[7];
  const float* bn1_b   = (const float*)d_in[8];
  const float* bn2_g   = (const float*)d_in[9];
  const float* bn2_b   = (const float*)d_in[10];
  const float* bn3_g   = (const float*)d_in[11];
  const float* bn3_b   = (const float*)d_in[12];
  const float* proj_w  = (const float*)d_in[13];
  const float* proj_b  = (const float*)d_in[14];
  const float* A       = (const float*)d_in[15];
  const float* Bm      = (const float*)d_in[16];
  const float* Cm      = (const float*)d_in[17];
  const float* out_w   = (const float*)d_in[18];
  const float* out_b   = (const float*)d_in[19];
  const float* g1_w    = (const float*)d_in[20];
  const float* g1_b    = (const float*)d_in[21];
  const float* g2_w    = (const float*)d_in[22];
  const float* g2_b    = (const float*)d_in[23];
  const float* h1_w    = (const float*)d_in[24];
  const float* h1_b    = (const float*)d_in[25];
  const float* h2_w    = (const float*)d_in[26];
  const float* h2_b    = (const float*)d_in[27];
  float* ws = (float*)d_ws;
  float* out = (float*)d_out;

  prep_kernel<<<64, 256, 0, stream>>>(conv1_w, conv1_b, conv2_w, conv2_b,
      conv3_w, conv3_b, bn1_g, bn1_b, bn2_g, bn2_b, bn3_g, bn3_b,
      proj_w, proj_b, A, Bm, Cm, out_w, g1_w, g2_w, h1_w, h2_w, ws);

  if (ws_size >= WS_NEED) {
    _Float16* a2gh = (_Float16*)(ws + OFF_A2);
    _Float16* a2gl = a2gh + (size_t)NB*640;
    conv12_kernel<<<NB/16, 512, 0, stream>>>(x, ws, a2gh, a2gl);
    conv3k_kernel<<<NB/16, 512, 0, stream>>>(ws, a2gh, a2gl, ws + OFF_SF);
  } else {
    conv_kernel<<<NB/(8*ITER), 256, 0, stream>>>(x, ws, ws + OFF_SF);
  }
  rnn_kernel<<<NB/64, 256, 0, stream>>>(x, ws, A, ws + OFF_H);
  tail_kernel<<<NB/64, 256, 0, stream>>>(ws, g1_b, g2_b, h1_b, h2_b, out_b, out);
}